// Round 1
// baseline (2763.468 us; speedup 1.0000x reference)
//
#include <hip/hip_runtime.h>

#define N_NODES 50000
#define N_EDGES 800000
#define NGRAPH  128
#define TILE    128   // block size for per-node kernels (2 waves)

// ---------------------------------------------------------------------------
// helpers
// ---------------------------------------------------------------------------

__device__ __forceinline__ float atomAddF(float* p, float v) {
#if defined(__gfx950__) || defined(__AMDGCN__)
    return unsafeAtomicAdd(p, v);   // native global_atomic_add_f32
#else
    return atomicAdd(p, v);
#endif
}

// acc[t] += sum_{k<kdim} lds_in[k*TILE+tid] * W[k*64+t]
// k-loop rolled (uniform weight addresses -> scalar loads), t-loop unrolled (regs)
__device__ __forceinline__ void gemv_acc(const float* __restrict__ W,
                                         const float* __restrict__ lds_in,
                                         int tid, int kdim, float* acc) {
#pragma unroll 1
    for (int k = 0; k < kdim; ++k) {
        float xk = lds_in[k * TILE + tid];
        const float* __restrict__ wr = W + k * 64;
#pragma unroll
        for (int t = 0; t < 64; ++t) acc[t] = fmaf(xk, wr[t], acc[t]);
    }
}

__device__ __forceinline__ void to_lds(float* __restrict__ lds, int tid,
                                       const float* acc, bool do_relu) {
#pragma unroll
    for (int t = 0; t < 64; ++t) {
        float x = acc[t];
        lds[t * TILE + tid] = do_relu ? fmaxf(x, 0.f) : x;
    }
}

__device__ __forceinline__ void store_row64(float* __restrict__ g, int n,
                                            const float* acc) {
    float4* g4 = (float4*)(g + (size_t)n * 64);
#pragma unroll
    for (int i = 0; i < 16; ++i)
        g4[i] = make_float4(acc[4 * i], acc[4 * i + 1], acc[4 * i + 2], acc[4 * i + 3]);
}

// ---------------------------------------------------------------------------
// kernel A: node_lin (16->64 relu ->64), then u = h@W1a, v = h@W1b + pos@W1c + b1
// ---------------------------------------------------------------------------
__global__ __launch_bounds__(TILE) void kA(
    const float* __restrict__ x, const float* __restrict__ pos,
    const float* __restrict__ nW1, const float* __restrict__ nb1,
    const float* __restrict__ nW2, const float* __restrict__ nb2,
    const float* __restrict__ lW1, const float* __restrict__ lb1,
    float* __restrict__ u, float* __restrict__ v) {
    __shared__ float smem[64 * TILE];
    int tid = threadIdx.x;
    int n = blockIdx.x * TILE + tid;
    if (n >= N_NODES) return;

    // x row (16 floats) -> lds slot
    const float4* x4 = (const float4*)(x + (size_t)n * 16);
#pragma unroll
    for (int i = 0; i < 4; ++i) {
        float4 a = x4[i];
        smem[(4 * i + 0) * TILE + tid] = a.x;
        smem[(4 * i + 1) * TILE + tid] = a.y;
        smem[(4 * i + 2) * TILE + tid] = a.z;
        smem[(4 * i + 3) * TILE + tid] = a.w;
    }

    float acc[64];
    // hid = relu(x@nW1 + nb1)
#pragma unroll
    for (int t = 0; t < 64; ++t) acc[t] = nb1[t];
    gemv_acc(nW1, smem, tid, 16, acc);
    to_lds(smem, tid, acc, true);

    // h = hid@nW2 + nb2   (no relu)
#pragma unroll
    for (int t = 0; t < 64; ++t) acc[t] = nb2[t];
    gemv_acc(nW2, smem, tid, 64, acc);
    to_lds(smem, tid, acc, false);

    // u = h @ W1a
#pragma unroll
    for (int t = 0; t < 64; ++t) acc[t] = 0.f;
    gemv_acc(lW1, smem, tid, 64, acc);
    store_row64(u, n, acc);

    // v = h @ W1b + pos @ W1c + b1
#pragma unroll
    for (int t = 0; t < 64; ++t) acc[t] = lb1[t];
    gemv_acc(lW1 + 64 * 64, smem, tid, 64, acc);
    float p0 = pos[(size_t)n * 3 + 0];
    float p1 = pos[(size_t)n * 3 + 1];
    float p2 = pos[(size_t)n * 3 + 2];
    const float* wp = lW1 + 128 * 64;
#pragma unroll
    for (int t = 0; t < 64; ++t)
        acc[t] += p0 * wp[t] + p1 * wp[64 + t] + p2 * wp[128 + t];
    store_row64(v, n, acc);
}

// ---------------------------------------------------------------------------
// degree kernel
// ---------------------------------------------------------------------------
__global__ void kDeg(const int* __restrict__ ei, int* __restrict__ deg) {
    int e = blockIdx.x * blockDim.x + threadIdx.x;
    if (e < N_EDGES) atomicAdd(&deg[ei[N_EDGES + e]], 1);
}

// ---------------------------------------------------------------------------
// edge kernel: aggH[dst] += relu(u[dst] + v[src])   (16 threads / edge, float4)
// ---------------------------------------------------------------------------
__global__ __launch_bounds__(256) void kEdge(const int* __restrict__ ei,
                                             const float* __restrict__ u,
                                             const float* __restrict__ v,
                                             float* __restrict__ aggH) {
    int tid = blockIdx.x * 256 + threadIdx.x;
    int e = tid >> 4;
    if (e >= N_EDGES) return;
    int c = (tid & 15) << 2;
    int s = ei[e];
    int d = ei[N_EDGES + e];
    float4 uu = *(const float4*)(u + (size_t)d * 64 + c);
    float4 vv = *(const float4*)(v + (size_t)s * 64 + c);
    float* dst = aggH + (size_t)d * 64 + c;
    atomAddF(dst + 0, fmaxf(uu.x + vv.x, 0.f));
    atomAddF(dst + 1, fmaxf(uu.y + vv.y, 0.f));
    atomAddF(dst + 2, fmaxf(uu.z + vv.z, 0.f));
    atomAddF(dst + 3, fmaxf(uu.w + vv.w, 0.f));
}

// ---------------------------------------------------------------------------
// kernel B (layers 0,1): aggH -> agg -> global_nn -> h -> next-layer u,v
// ---------------------------------------------------------------------------
__global__ __launch_bounds__(TILE) void kB(
    const float* __restrict__ aggH, const float* __restrict__ pos,
    const int* __restrict__ deg,
    const float* __restrict__ lW2, const float* __restrict__ lb2,
    const float* __restrict__ gW1, const float* __restrict__ gb1,
    const float* __restrict__ gW2, const float* __restrict__ gb2,
    const float* __restrict__ W1n, const float* __restrict__ b1n,
    float* __restrict__ u, float* __restrict__ v) {
    __shared__ float smem[64 * TILE];
    int tid = threadIdx.x;
    int n = blockIdx.x * TILE + tid;
    if (n >= N_NODES) return;

    const float4* a4 = (const float4*)(aggH + (size_t)n * 64);
#pragma unroll
    for (int i = 0; i < 16; ++i) {
        float4 a = a4[i];
        smem[(4 * i + 0) * TILE + tid] = a.x;
        smem[(4 * i + 1) * TILE + tid] = a.y;
        smem[(4 * i + 2) * TILE + tid] = a.z;
        smem[(4 * i + 3) * TILE + tid] = a.w;
    }
    float dg = (float)deg[n];

    float acc[64];
    // agg = aggH@lW2 + deg*lb2
#pragma unroll
    for (int t = 0; t < 64; ++t) acc[t] = dg * lb2[t];
    gemv_acc(lW2, smem, tid, 64, acc);
    to_lds(smem, tid, acc, false);

    // t1 = relu(agg@gW1 + gb1)
#pragma unroll
    for (int t = 0; t < 64; ++t) acc[t] = gb1[t];
    gemv_acc(gW1, smem, tid, 64, acc);
    to_lds(smem, tid, acc, true);

    // h = relu(t1@gW2 + gb2)
#pragma unroll
    for (int t = 0; t < 64; ++t) acc[t] = gb2[t];
    gemv_acc(gW2, smem, tid, 64, acc);
    to_lds(smem, tid, acc, true);

    // u = h@W1a(next)
#pragma unroll
    for (int t = 0; t < 64; ++t) acc[t] = 0.f;
    gemv_acc(W1n, smem, tid, 64, acc);
    store_row64(u, n, acc);

    // v = h@W1b + pos@W1c + b1 (next)
#pragma unroll
    for (int t = 0; t < 64; ++t) acc[t] = b1n[t];
    gemv_acc(W1n + 64 * 64, smem, tid, 64, acc);
    float p0 = pos[(size_t)n * 3 + 0];
    float p1 = pos[(size_t)n * 3 + 1];
    float p2 = pos[(size_t)n * 3 + 2];
    const float* wp = W1n + 128 * 64;
#pragma unroll
    for (int t = 0; t < 64; ++t)
        acc[t] += p0 * wp[t] + p1 * wp[64 + t] + p2 * wp[128 + t];
    store_row64(v, n, acc);
}

// ---------------------------------------------------------------------------
// kernel C (layer 2): aggH -> agg -> global_nn -> h -> lin1 relu lin2 -> readout
// ---------------------------------------------------------------------------
__global__ __launch_bounds__(TILE) void kC(
    const float* __restrict__ aggH, const int* __restrict__ deg,
    const int* __restrict__ batch,
    const float* __restrict__ lW2, const float* __restrict__ lb2,
    const float* __restrict__ gW1, const float* __restrict__ gb1,
    const float* __restrict__ gW2, const float* __restrict__ gb2,
    const float* __restrict__ lin1W, const float* __restrict__ lin1b,
    const float* __restrict__ lin2W, const float* __restrict__ lin2b,
    float* __restrict__ out) {
    __shared__ float smem[64 * TILE];
    int tid = threadIdx.x;
    int n = blockIdx.x * TILE + tid;
    if (n >= N_NODES) return;

    const float4* a4 = (const float4*)(aggH + (size_t)n * 64);
#pragma unroll
    for (int i = 0; i < 16; ++i) {
        float4 a = a4[i];
        smem[(4 * i + 0) * TILE + tid] = a.x;
        smem[(4 * i + 1) * TILE + tid] = a.y;
        smem[(4 * i + 2) * TILE + tid] = a.z;
        smem[(4 * i + 3) * TILE + tid] = a.w;
    }
    float dg = (float)deg[n];

    float acc[64];
#pragma unroll
    for (int t = 0; t < 64; ++t) acc[t] = dg * lb2[t];
    gemv_acc(lW2, smem, tid, 64, acc);
    to_lds(smem, tid, acc, false);

#pragma unroll
    for (int t = 0; t < 64; ++t) acc[t] = gb1[t];
    gemv_acc(gW1, smem, tid, 64, acc);
    to_lds(smem, tid, acc, true);

#pragma unroll
    for (int t = 0; t < 64; ++t) acc[t] = gb2[t];
    gemv_acc(gW2, smem, tid, 64, acc);
    to_lds(smem, tid, acc, true);

    // p = relu(h@lin1W + lin1b)  (64 -> 32)
    float accp[32];
#pragma unroll
    for (int j = 0; j < 32; ++j) accp[j] = lin1b[j];
#pragma unroll 1
    for (int k = 0; k < 64; ++k) {
        float hk = smem[k * TILE + tid];
        const float* __restrict__ wr = lin1W + k * 32;
#pragma unroll
        for (int j = 0; j < 32; ++j) accp[j] = fmaf(hk, wr[j], accp[j]);
    }
#pragma unroll
    for (int j = 0; j < 32; ++j) smem[j * TILE + tid] = fmaxf(accp[j], 0.f);

    // o = p@lin2W + lin2b  (32 -> 8)
    float acco[8];
#pragma unroll
    for (int c = 0; c < 8; ++c) acco[c] = lin2b[c];
#pragma unroll 1
    for (int j = 0; j < 32; ++j) {
        float pj = smem[j * TILE + tid];
        const float* __restrict__ wr = lin2W + j * 8;
#pragma unroll
        for (int c = 0; c < 8; ++c) acco[c] = fmaf(pj, wr[c], acco[c]);
    }

    int g = batch[n];
#pragma unroll
    for (int c = 0; c < 8; ++c) atomAddF(&out[g * 8 + c], acco[c]);
}

// ---------------------------------------------------------------------------
// launch
// ---------------------------------------------------------------------------
extern "C" void kernel_launch(void* const* d_in, const int* in_sizes, int n_in,
                              void* d_out, int out_size, void* d_ws, size_t ws_size,
                              hipStream_t stream) {
    const float* x     = (const float*)d_in[0];
    const float* pos   = (const float*)d_in[1];
    const int*   ei    = (const int*)d_in[2];
    const int*   batch = (const int*)d_in[3];
    const float* nW1   = (const float*)d_in[4];
    const float* nb1   = (const float*)d_in[5];
    const float* nW2   = (const float*)d_in[6];
    const float* nb2   = (const float*)d_in[7];
    const float* lW1   = (const float*)d_in[8];
    const float* lb1   = (const float*)d_in[9];
    const float* lW2   = (const float*)d_in[10];
    const float* lb2   = (const float*)d_in[11];
    const float* gW1   = (const float*)d_in[12];
    const float* gb1   = (const float*)d_in[13];
    const float* gW2   = (const float*)d_in[14];
    const float* gb2   = (const float*)d_in[15];
    const float* lin1W = (const float*)d_in[16];
    const float* lin1b = (const float*)d_in[17];
    const float* lin2W = (const float*)d_in[18];
    const float* lin2b = (const float*)d_in[19];
    float* out = (float*)d_out;

    float* u    = (float*)d_ws;          // N*64
    float* v    = u + (size_t)N_NODES * 64;
    float* aggH = v + (size_t)N_NODES * 64;
    int*   deg  = (int*)(aggH + (size_t)N_NODES * 64);

    const int nodeBlocks = (N_NODES + TILE - 1) / TILE;
    const int edgeBlocks = (N_EDGES * 16 + 255) / 256;

    hipMemsetAsync(deg, 0, N_NODES * sizeof(int), stream);
    hipMemsetAsync(out, 0, (size_t)out_size * sizeof(float), stream);
    kDeg<<<(N_EDGES + 255) / 256, 256, 0, stream>>>(ei, deg);

    kA<<<nodeBlocks, TILE, 0, stream>>>(x, pos, nW1, nb1, nW2, nb2,
                                        lW1, lb1, u, v);

    for (int l = 0; l < 3; ++l) {
        hipMemsetAsync(aggH, 0, (size_t)N_NODES * 64 * sizeof(float), stream);
        kEdge<<<edgeBlocks, 256, 0, stream>>>(ei, u, v, aggH);
        if (l < 2) {
            kB<<<nodeBlocks, TILE, 0, stream>>>(
                aggH, pos, deg,
                lW2 + l * 64 * 64, lb2 + l * 64,
                gW1 + l * 64 * 64, gb1 + l * 64,
                gW2 + l * 64 * 64, gb2 + l * 64,
                lW1 + (l + 1) * 131 * 64, lb1 + (l + 1) * 64,
                u, v);
        } else {
            kC<<<nodeBlocks, TILE, 0, stream>>>(
                aggH, deg, batch,
                lW2 + l * 64 * 64, lb2 + l * 64,
                gW1 + l * 64 * 64, gb1 + l * 64,
                gW2 + l * 64 * 64, gb2 + l * 64,
                lin1W, lin1b, lin2W, lin2b, out);
        }
    }
}

// Round 2
// 902.229 us; speedup vs baseline: 3.0629x; 3.0629x over previous
//
#include <hip/hip_runtime.h>

#define N_NODES 50000
#define N_EDGES 800000
#define NGRAPH  128
#define TILE    128   // block size for per-node kernels (2 waves)
#define NCHUNK  ((N_NODES + 255) / 256)   // 196 chunks for the scan

// ---------------------------------------------------------------------------
// helpers
// ---------------------------------------------------------------------------

__device__ __forceinline__ float atomAddF(float* p, float v) {
#if defined(__gfx950__) || defined(__AMDGCN__)
    return unsafeAtomicAdd(p, v);
#else
    return atomicAdd(p, v);
#endif
}

// acc[t] += sum_{k<kdim} lds_in[k*TILE+tid] * W[k*64+t]
__device__ __forceinline__ void gemv_acc(const float* __restrict__ W,
                                         const float* __restrict__ lds_in,
                                         int tid, int kdim, float* acc) {
#pragma unroll 1
    for (int k = 0; k < kdim; ++k) {
        float xk = lds_in[k * TILE + tid];
        const float* __restrict__ wr = W + k * 64;
#pragma unroll
        for (int t = 0; t < 64; ++t) acc[t] = fmaf(xk, wr[t], acc[t]);
    }
}

__device__ __forceinline__ void to_lds(float* __restrict__ lds, int tid,
                                       const float* acc, bool do_relu) {
#pragma unroll
    for (int t = 0; t < 64; ++t) {
        float x = acc[t];
        lds[t * TILE + tid] = do_relu ? fmaxf(x, 0.f) : x;
    }
}

__device__ __forceinline__ void store_row64(float* __restrict__ g, int n,
                                            const float* acc) {
    float4* g4 = (float4*)(g + (size_t)n * 64);
#pragma unroll
    for (int i = 0; i < 16; ++i)
        g4[i] = make_float4(acc[4 * i], acc[4 * i + 1], acc[4 * i + 2], acc[4 * i + 3]);
}

// ---------------------------------------------------------------------------
// CSR build: histogram -> 2-level exclusive scan -> scatter
// ---------------------------------------------------------------------------
__global__ void kDeg(const int* __restrict__ ei, int* __restrict__ cnt) {
    int e = blockIdx.x * blockDim.x + threadIdx.x;
    if (e < N_EDGES) atomicAdd(&cnt[ei[N_EDGES + e]], 1);
}

__global__ __launch_bounds__(256) void kBlockSum(const int* __restrict__ cnt,
                                                 int* __restrict__ blockSums) {
    __shared__ int s[256];
    int i = threadIdx.x;
    int n = blockIdx.x * 256 + i;
    s[i] = (n < N_NODES) ? cnt[n] : 0;
    __syncthreads();
#pragma unroll
    for (int off = 128; off > 0; off >>= 1) {
        if (i < off) s[i] += s[i + off];
        __syncthreads();
    }
    if (i == 0) blockSums[blockIdx.x] = s[0];
}

// exclusive scan of NCHUNK block sums (single block of 256)
__global__ __launch_bounds__(256) void kScanSmall(const int* __restrict__ blockSums,
                                                  int* __restrict__ chunkOff) {
    __shared__ int s[256];
    int i = threadIdx.x;
    int val = (i < NCHUNK) ? blockSums[i] : 0;
    s[i] = val;
    __syncthreads();
#pragma unroll
    for (int off = 1; off < 256; off <<= 1) {
        int t = (i >= off) ? s[i - off] : 0;
        __syncthreads();
        s[i] += t;
        __syncthreads();
    }
    chunkOff[i] = s[i] - val;   // exclusive
}

// per-chunk exclusive scan + chunk offset -> rowPtr; also init cursor = rowPtr
// NOTE: cnt and cursor may be the same buffer (each index read-then-written by
// exactly one thread).
__global__ __launch_bounds__(256) void kRowPtr(const int* __restrict__ cnt,
                                               const int* __restrict__ chunkOff,
                                               int* __restrict__ rowPtr,
                                               int* __restrict__ cursor) {
    __shared__ int s[256];
    int i = threadIdx.x;
    int n = blockIdx.x * 256 + i;
    int val = (n < N_NODES) ? cnt[n] : 0;
    s[i] = val;
    __syncthreads();
#pragma unroll
    for (int off = 1; off < 256; off <<= 1) {
        int t = (i >= off) ? s[i - off] : 0;
        __syncthreads();
        s[i] += t;
        __syncthreads();
    }
    if (n < N_NODES) {
        int ex = chunkOff[blockIdx.x] + s[i] - val;
        rowPtr[n] = ex;
        cursor[n] = ex;
        if (n == N_NODES - 1) rowPtr[N_NODES] = ex + val;  // == E
    }
}

__global__ void kScatter(const int* __restrict__ ei, int* __restrict__ cursor,
                         int* __restrict__ srcList) {
    int e = blockIdx.x * blockDim.x + threadIdx.x;
    if (e >= N_EDGES) return;
    int s = ei[e];
    int d = ei[N_EDGES + e];
    int idx = atomicAdd(&cursor[d], 1);
    srcList[idx] = s;
}

// ---------------------------------------------------------------------------
// aggregation: one wave per node, lane = channel.
// aggH[n][lane] = sum_{src in inedges(n)} relu(u[n][lane] + v[src][lane])
// aggH may alias u (u row is read into a register before the loop).
// ---------------------------------------------------------------------------
__global__ __launch_bounds__(256) void kAgg(const int* __restrict__ rowPtr,
                                            const int* __restrict__ srcList,
                                            const float* __restrict__ u,
                                            const float* __restrict__ v,
                                            float* __restrict__ aggH) {
    int gt = blockIdx.x * 256 + threadIdx.x;
    int n = gt >> 6;
    int lane = gt & 63;
    if (n >= N_NODES) return;
    float ut = u[(size_t)n * 64 + lane];
    int b = rowPtr[n], e = rowPtr[n + 1];
    float acc = 0.f;
    int i = b;
    for (; i + 1 < e; i += 2) {
        int s0 = srcList[i];
        int s1 = srcList[i + 1];
        float v0 = v[(size_t)s0 * 64 + lane];
        float v1 = v[(size_t)s1 * 64 + lane];
        acc += fmaxf(ut + v0, 0.f) + fmaxf(ut + v1, 0.f);
    }
    if (i < e) {
        int s0 = srcList[i];
        acc += fmaxf(ut + v[(size_t)s0 * 64 + lane], 0.f);
    }
    aggH[(size_t)n * 64 + lane] = acc;
}

// ---------------------------------------------------------------------------
// kernel A: node_lin (16->64 relu ->64), then u = h@W1a, v = h@W1b + pos@W1c + b1
// ---------------------------------------------------------------------------
__global__ __launch_bounds__(TILE) void kA(
    const float* __restrict__ x, const float* __restrict__ pos,
    const float* __restrict__ nW1, const float* __restrict__ nb1,
    const float* __restrict__ nW2, const float* __restrict__ nb2,
    const float* __restrict__ lW1, const float* __restrict__ lb1,
    float* __restrict__ u, float* __restrict__ v) {
    __shared__ float smem[64 * TILE];
    int tid = threadIdx.x;
    int n = blockIdx.x * TILE + tid;
    if (n >= N_NODES) return;

    const float4* x4 = (const float4*)(x + (size_t)n * 16);
#pragma unroll
    for (int i = 0; i < 4; ++i) {
        float4 a = x4[i];
        smem[(4 * i + 0) * TILE + tid] = a.x;
        smem[(4 * i + 1) * TILE + tid] = a.y;
        smem[(4 * i + 2) * TILE + tid] = a.z;
        smem[(4 * i + 3) * TILE + tid] = a.w;
    }

    float acc[64];
#pragma unroll
    for (int t = 0; t < 64; ++t) acc[t] = nb1[t];
    gemv_acc(nW1, smem, tid, 16, acc);
    to_lds(smem, tid, acc, true);

#pragma unroll
    for (int t = 0; t < 64; ++t) acc[t] = nb2[t];
    gemv_acc(nW2, smem, tid, 64, acc);
    to_lds(smem, tid, acc, false);

#pragma unroll
    for (int t = 0; t < 64; ++t) acc[t] = 0.f;
    gemv_acc(lW1, smem, tid, 64, acc);
    store_row64(u, n, acc);

#pragma unroll
    for (int t = 0; t < 64; ++t) acc[t] = lb1[t];
    gemv_acc(lW1 + 64 * 64, smem, tid, 64, acc);
    float p0 = pos[(size_t)n * 3 + 0];
    float p1 = pos[(size_t)n * 3 + 1];
    float p2 = pos[(size_t)n * 3 + 2];
    const float* wp = lW1 + 128 * 64;
#pragma unroll
    for (int t = 0; t < 64; ++t)
        acc[t] += p0 * wp[t] + p1 * wp[64 + t] + p2 * wp[128 + t];
    store_row64(v, n, acc);
}

// ---------------------------------------------------------------------------
// kernel B (layers 0,1): aggH -> agg -> global_nn -> h -> next-layer u,v
// aggH may alias u (row read into LDS before u row is written).
// ---------------------------------------------------------------------------
__global__ __launch_bounds__(TILE) void kB(
    const float* __restrict__ aggH, const float* __restrict__ pos,
    const int* __restrict__ rowPtr,
    const float* __restrict__ lW2, const float* __restrict__ lb2,
    const float* __restrict__ gW1, const float* __restrict__ gb1,
    const float* __restrict__ gW2, const float* __restrict__ gb2,
    const float* __restrict__ W1n, const float* __restrict__ b1n,
    float* __restrict__ u, float* __restrict__ v) {
    __shared__ float smem[64 * TILE];
    int tid = threadIdx.x;
    int n = blockIdx.x * TILE + tid;
    if (n >= N_NODES) return;

    const float4* a4 = (const float4*)(aggH + (size_t)n * 64);
#pragma unroll
    for (int i = 0; i < 16; ++i) {
        float4 a = a4[i];
        smem[(4 * i + 0) * TILE + tid] = a.x;
        smem[(4 * i + 1) * TILE + tid] = a.y;
        smem[(4 * i + 2) * TILE + tid] = a.z;
        smem[(4 * i + 3) * TILE + tid] = a.w;
    }
    float dg = (float)(rowPtr[n + 1] - rowPtr[n]);

    float acc[64];
#pragma unroll
    for (int t = 0; t < 64; ++t) acc[t] = dg * lb2[t];
    gemv_acc(lW2, smem, tid, 64, acc);
    to_lds(smem, tid, acc, false);

#pragma unroll
    for (int t = 0; t < 64; ++t) acc[t] = gb1[t];
    gemv_acc(gW1, smem, tid, 64, acc);
    to_lds(smem, tid, acc, true);

#pragma unroll
    for (int t = 0; t < 64; ++t) acc[t] = gb2[t];
    gemv_acc(gW2, smem, tid, 64, acc);
    to_lds(smem, tid, acc, true);

#pragma unroll
    for (int t = 0; t < 64; ++t) acc[t] = 0.f;
    gemv_acc(W1n, smem, tid, 64, acc);
    store_row64(u, n, acc);

#pragma unroll
    for (int t = 0; t < 64; ++t) acc[t] = b1n[t];
    gemv_acc(W1n + 64 * 64, smem, tid, 64, acc);
    float p0 = pos[(size_t)n * 3 + 0];
    float p1 = pos[(size_t)n * 3 + 1];
    float p2 = pos[(size_t)n * 3 + 2];
    const float* wp = W1n + 128 * 64;
#pragma unroll
    for (int t = 0; t < 64; ++t)
        acc[t] += p0 * wp[t] + p1 * wp[64 + t] + p2 * wp[128 + t];
    store_row64(v, n, acc);
}

// ---------------------------------------------------------------------------
// kernel C (layer 2): aggH -> agg -> global_nn -> h -> lin1 relu lin2 -> readout
// ---------------------------------------------------------------------------
__global__ __launch_bounds__(TILE) void kC(
    const float* __restrict__ aggH, const int* __restrict__ rowPtr,
    const int* __restrict__ batch,
    const float* __restrict__ lW2, const float* __restrict__ lb2,
    const float* __restrict__ gW1, const float* __restrict__ gb1,
    const float* __restrict__ gW2, const float* __restrict__ gb2,
    const float* __restrict__ lin1W, const float* __restrict__ lin1b,
    const float* __restrict__ lin2W, const float* __restrict__ lin2b,
    float* __restrict__ out) {
    __shared__ float smem[64 * TILE];
    int tid = threadIdx.x;
    int n = blockIdx.x * TILE + tid;
    if (n >= N_NODES) return;

    const float4* a4 = (const float4*)(aggH + (size_t)n * 64);
#pragma unroll
    for (int i = 0; i < 16; ++i) {
        float4 a = a4[i];
        smem[(4 * i + 0) * TILE + tid] = a.x;
        smem[(4 * i + 1) * TILE + tid] = a.y;
        smem[(4 * i + 2) * TILE + tid] = a.z;
        smem[(4 * i + 3) * TILE + tid] = a.w;
    }
    float dg = (float)(rowPtr[n + 1] - rowPtr[n]);

    float acc[64];
#pragma unroll
    for (int t = 0; t < 64; ++t) acc[t] = dg * lb2[t];
    gemv_acc(lW2, smem, tid, 64, acc);
    to_lds(smem, tid, acc, false);

#pragma unroll
    for (int t = 0; t < 64; ++t) acc[t] = gb1[t];
    gemv_acc(gW1, smem, tid, 64, acc);
    to_lds(smem, tid, acc, true);

#pragma unroll
    for (int t = 0; t < 64; ++t) acc[t] = gb2[t];
    gemv_acc(gW2, smem, tid, 64, acc);
    to_lds(smem, tid, acc, true);

    float accp[32];
#pragma unroll
    for (int j = 0; j < 32; ++j) accp[j] = lin1b[j];
#pragma unroll 1
    for (int k = 0; k < 64; ++k) {
        float hk = smem[k * TILE + tid];
        const float* __restrict__ wr = lin1W + k * 32;
#pragma unroll
        for (int j = 0; j < 32; ++j) accp[j] = fmaf(hk, wr[j], accp[j]);
    }
#pragma unroll
    for (int j = 0; j < 32; ++j) smem[j * TILE + tid] = fmaxf(accp[j], 0.f);

    float acco[8];
#pragma unroll
    for (int c = 0; c < 8; ++c) acco[c] = lin2b[c];
#pragma unroll 1
    for (int j = 0; j < 32; ++j) {
        float pj = smem[j * TILE + tid];
        const float* __restrict__ wr = lin2W + j * 8;
#pragma unroll
        for (int c = 0; c < 8; ++c) acco[c] = fmaf(pj, wr[c], acco[c]);
    }

    int g = batch[n];
#pragma unroll
    for (int c = 0; c < 8; ++c) atomAddF(&out[g * 8 + c], acco[c]);
}

// ---------------------------------------------------------------------------
// launch
// ---------------------------------------------------------------------------
extern "C" void kernel_launch(void* const* d_in, const int* in_sizes, int n_in,
                              void* d_out, int out_size, void* d_ws, size_t ws_size,
                              hipStream_t stream) {
    const float* x     = (const float*)d_in[0];
    const float* pos   = (const float*)d_in[1];
    const int*   ei    = (const int*)d_in[2];
    const int*   batch = (const int*)d_in[3];
    const float* nW1   = (const float*)d_in[4];
    const float* nb1   = (const float*)d_in[5];
    const float* nW2   = (const float*)d_in[6];
    const float* nb2   = (const float*)d_in[7];
    const float* lW1   = (const float*)d_in[8];
    const float* lb1   = (const float*)d_in[9];
    const float* lW2   = (const float*)d_in[10];
    const float* lb2   = (const float*)d_in[11];
    const float* gW1   = (const float*)d_in[12];
    const float* gb1   = (const float*)d_in[13];
    const float* gW2   = (const float*)d_in[14];
    const float* gb2   = (const float*)d_in[15];
    const float* lin1W = (const float*)d_in[16];
    const float* lin1b = (const float*)d_in[17];
    const float* lin2W = (const float*)d_in[18];
    const float* lin2b = (const float*)d_in[19];
    float* out = (float*)d_out;

    // workspace layout (aggH aliases u)
    float* u       = (float*)d_ws;                        // N*64 floats (also aggH)
    float* v       = u + (size_t)N_NODES * 64;            // N*64 floats
    int*   cursor  = (int*)(v + (size_t)N_NODES * 64);    // N ints (also histogram cnt)
    int*   rowPtr  = cursor + N_NODES;                    // N+1 ints
    int*   srcList = rowPtr + N_NODES + 1;                // E ints
    int*   blockSums = srcList + N_EDGES;                 // 256 ints
    int*   chunkOff  = blockSums + 256;                   // 256 ints
    float* aggH = u;

    const int nodeBlocks = (N_NODES + TILE - 1) / TILE;
    const int edgeBlocks = (N_EDGES + 255) / 256;
    const int aggBlocks  = (N_NODES * 64 + 255) / 256;

    hipMemsetAsync(cursor, 0, N_NODES * sizeof(int), stream);
    hipMemsetAsync(out, 0, (size_t)out_size * sizeof(float), stream);

    // CSR build
    kDeg<<<edgeBlocks, 256, 0, stream>>>(ei, cursor);
    kBlockSum<<<NCHUNK, 256, 0, stream>>>(cursor, blockSums);
    kScanSmall<<<1, 256, 0, stream>>>(blockSums, chunkOff);
    kRowPtr<<<NCHUNK, 256, 0, stream>>>(cursor, chunkOff, rowPtr, cursor);
    kScatter<<<edgeBlocks, 256, 0, stream>>>(ei, cursor, srcList);

    kA<<<nodeBlocks, TILE, 0, stream>>>(x, pos, nW1, nb1, nW2, nb2,
                                        lW1, lb1, u, v);

    for (int l = 0; l < 3; ++l) {
        kAgg<<<aggBlocks, 256, 0, stream>>>(rowPtr, srcList, u, v, aggH);
        if (l < 2) {
            kB<<<nodeBlocks, TILE, 0, stream>>>(
                aggH, pos, rowPtr,
                lW2 + l * 64 * 64, lb2 + l * 64,
                gW1 + l * 64 * 64, gb1 + l * 64,
                gW2 + l * 64 * 64, gb2 + l * 64,
                lW1 + (l + 1) * 131 * 64, lb1 + (l + 1) * 64,
                u, v);
        } else {
            kC<<<nodeBlocks, TILE, 0, stream>>>(
                aggH, rowPtr, batch,
                lW2 + l * 64 * 64, lb2 + l * 64,
                gW1 + l * 64 * 64, gb1 + l * 64,
                gW2 + l * 64 * 64, gb2 + l * 64,
                lin1W, lin1b, lin2W, lin2b, out);
        }
    }
}

// Round 3
// 643.312 us; speedup vs baseline: 4.2957x; 1.4025x over previous
//
#include <hip/hip_runtime.h>

#define N_NODES 50000
#define N_EDGES 800000
#define NGRAPH  128
#define NCHUNK  ((N_NODES + 255) / 256)
#define PITCH   65          // LDS pitch (64+1) to break power-of-2 strides

// ---------------------------------------------------------------------------
// helpers
// ---------------------------------------------------------------------------

__device__ __forceinline__ float atomAddF(float* p, float v) {
#if defined(__gfx950__) || defined(__AMDGCN__)
    return unsafeAtomicAdd(p, v);
#else
    return atomicAdd(p, v);
#endif
}

// One GEMV stage slice: acc[j] += sum_k sIn[k][lane] * W[k][tbase+j]
// W rows are wave-uniform (tbase from readfirstlane) -> scalar loads.
template<int K, int TPW, int LDW>
__device__ __forceinline__ void stage_gemv(const float* __restrict__ W,
                                           const float* __restrict__ sIn,
                                           int lane, int tbase, float* acc) {
#pragma unroll 1
    for (int k = 0; k < K; ++k) {
        float xk = sIn[k * PITCH + lane];
        const float* __restrict__ wr = W + k * LDW + tbase;
#pragma unroll
        for (int j = 0; j < TPW; ++j) acc[j] = fmaf(xk, wr[j], acc[j]);
    }
}

// in-place safe: sync (all reads done) -> write -> sync (visible)
template<int TPW>
__device__ __forceinline__ void stage_store(float* __restrict__ s, int lane,
                                            int tbase, const float* acc,
                                            bool do_relu) {
    __syncthreads();
#pragma unroll
    for (int j = 0; j < TPW; ++j) {
        float x = acc[j];
        s[(tbase + j) * PITCH + lane] = do_relu ? fmaxf(x, 0.f) : x;
    }
    __syncthreads();
}

// store 16 consecutive channels of row n as 4x float4
__device__ __forceinline__ void store_slice16(float* __restrict__ g, int n,
                                              int tbase, const float* acc) {
    float4* g4 = (float4*)(g + (size_t)n * 64 + tbase);
#pragma unroll
    for (int i = 0; i < 4; ++i)
        g4[i] = make_float4(acc[4 * i], acc[4 * i + 1], acc[4 * i + 2], acc[4 * i + 3]);
}

// ---------------------------------------------------------------------------
// CSR build: histogram -> 2-level exclusive scan -> scatter
// ---------------------------------------------------------------------------
__global__ void kDeg(const int* __restrict__ ei, int* __restrict__ cnt) {
    int e = blockIdx.x * blockDim.x + threadIdx.x;
    if (e < N_EDGES) atomicAdd(&cnt[ei[N_EDGES + e]], 1);
}

__global__ __launch_bounds__(256) void kBlockSum(const int* __restrict__ cnt,
                                                 int* __restrict__ blockSums) {
    __shared__ int s[256];
    int i = threadIdx.x;
    int n = blockIdx.x * 256 + i;
    s[i] = (n < N_NODES) ? cnt[n] : 0;
    __syncthreads();
#pragma unroll
    for (int off = 128; off > 0; off >>= 1) {
        if (i < off) s[i] += s[i + off];
        __syncthreads();
    }
    if (i == 0) blockSums[blockIdx.x] = s[0];
}

__global__ __launch_bounds__(256) void kScanSmall(const int* __restrict__ blockSums,
                                                  int* __restrict__ chunkOff) {
    __shared__ int s[256];
    int i = threadIdx.x;
    int val = (i < NCHUNK) ? blockSums[i] : 0;
    s[i] = val;
    __syncthreads();
#pragma unroll
    for (int off = 1; off < 256; off <<= 1) {
        int t = (i >= off) ? s[i - off] : 0;
        __syncthreads();
        s[i] += t;
        __syncthreads();
    }
    chunkOff[i] = s[i] - val;
}

__global__ __launch_bounds__(256) void kRowPtr(const int* __restrict__ cnt,
                                               const int* __restrict__ chunkOff,
                                               int* __restrict__ rowPtr,
                                               int* __restrict__ cursor) {
    __shared__ int s[256];
    int i = threadIdx.x;
    int n = blockIdx.x * 256 + i;
    int val = (n < N_NODES) ? cnt[n] : 0;
    s[i] = val;
    __syncthreads();
#pragma unroll
    for (int off = 1; off < 256; off <<= 1) {
        int t = (i >= off) ? s[i - off] : 0;
        __syncthreads();
        s[i] += t;
        __syncthreads();
    }
    if (n < N_NODES) {
        int ex = chunkOff[blockIdx.x] + s[i] - val;
        rowPtr[n] = ex;
        cursor[n] = ex;
        if (n == N_NODES - 1) rowPtr[N_NODES] = ex + val;
    }
}

__global__ void kScatter(const int* __restrict__ ei, int* __restrict__ cursor,
                         int* __restrict__ srcList) {
    int e = blockIdx.x * blockDim.x + threadIdx.x;
    if (e >= N_EDGES) return;
    int s = ei[e];
    int d = ei[N_EDGES + e];
    int idx = atomicAdd(&cursor[d], 1);
    srcList[idx] = s;
}

// ---------------------------------------------------------------------------
// aggregation: one wave per node, lane = channel (zero atomics; aggH may alias u)
// ---------------------------------------------------------------------------
__global__ __launch_bounds__(256) void kAgg(const int* __restrict__ rowPtr,
                                            const int* __restrict__ srcList,
                                            const float* __restrict__ u,
                                            const float* __restrict__ v,
                                            float* __restrict__ aggH) {
    int gt = blockIdx.x * 256 + threadIdx.x;
    int n = gt >> 6;
    int lane = gt & 63;
    if (n >= N_NODES) return;
    float ut = u[(size_t)n * 64 + lane];
    int b = rowPtr[n], e = rowPtr[n + 1];
    float acc = 0.f;
    int i = b;
    for (; i + 1 < e; i += 2) {
        int s0 = srcList[i];
        int s1 = srcList[i + 1];
        float v0 = v[(size_t)s0 * 64 + lane];
        float v1 = v[(size_t)s1 * 64 + lane];
        acc += fmaxf(ut + v0, 0.f) + fmaxf(ut + v1, 0.f);
    }
    if (i < e) {
        int s0 = srcList[i];
        acc += fmaxf(ut + v[(size_t)s0 * 64 + lane], 0.f);
    }
    aggH[(size_t)n * 64 + lane] = acc;
}

// ---------------------------------------------------------------------------
// kA: node_lin (16->64 relu ->64) then u = h@W1a, v = h@W1b + pos@W1c + b1
// 64 nodes/block, 4 waves; lane=node, wave w computes out slice [16w,16w+16)
// ---------------------------------------------------------------------------
__global__ __launch_bounds__(256) void kA(
    const float* __restrict__ x, const float* __restrict__ pos,
    const float* __restrict__ nW1, const float* __restrict__ nb1,
    const float* __restrict__ nW2, const float* __restrict__ nb2,
    const float* __restrict__ lW1, const float* __restrict__ lb1,
    float* __restrict__ u, float* __restrict__ v) {
    __shared__ float smem[64 * PITCH];
    int tid = threadIdx.x;
    int lane = tid & 63;
    int wv = __builtin_amdgcn_readfirstlane(tid >> 6);
    int tb = wv * 16;
    int nodeBase = blockIdx.x * 64;
    int nvalid = min(64, N_NODES - nodeBase);
    int n = nodeBase + lane;
    bool act = lane < nvalid;

    // stage x[node][16] -> smem[ch][node]
    for (int idx = tid; idx < nvalid * 16; idx += 256) {
        int nl = idx >> 4, ch = idx & 15;
        smem[ch * PITCH + nl] = x[(size_t)nodeBase * 16 + idx];
    }
    __syncthreads();

    float acc[16];
    // s1: relu(x@nW1 + nb1)
#pragma unroll
    for (int j = 0; j < 16; ++j) acc[j] = nb1[tb + j];
    stage_gemv<16, 16, 64>(nW1, smem, lane, tb, acc);
    stage_store<16>(smem, lane, tb, acc, true);

    // s2: h = @nW2 + nb2
#pragma unroll
    for (int j = 0; j < 16; ++j) acc[j] = nb2[tb + j];
    stage_gemv<64, 16, 64>(nW2, smem, lane, tb, acc);
    stage_store<16>(smem, lane, tb, acc, false);

    // s3: u = h@W1a
#pragma unroll
    for (int j = 0; j < 16; ++j) acc[j] = 0.f;
    stage_gemv<64, 16, 64>(lW1, smem, lane, tb, acc);
    if (act) store_slice16(u, n, tb, acc);

    // s4: v = h@W1b + pos@W1c + b1
#pragma unroll
    for (int j = 0; j < 16; ++j) acc[j] = lb1[tb + j];
    stage_gemv<64, 16, 64>(lW1 + 64 * 64, smem, lane, tb, acc);
    float p0 = 0.f, p1 = 0.f, p2 = 0.f;
    if (act) {
        p0 = pos[(size_t)n * 3 + 0];
        p1 = pos[(size_t)n * 3 + 1];
        p2 = pos[(size_t)n * 3 + 2];
    }
    const float* __restrict__ wp = lW1 + 128 * 64 + tb;
#pragma unroll
    for (int j = 0; j < 16; ++j)
        acc[j] += p0 * wp[j] + p1 * wp[64 + j] + p2 * wp[128 + j];
    if (act) store_slice16(v, n, tb, acc);
}

// ---------------------------------------------------------------------------
// stage aggH[64 nodes][64 ch] -> smem[ch][node] (float4 global loads)
// ---------------------------------------------------------------------------
__device__ __forceinline__ void load_agg(const float* __restrict__ aggH,
                                         float* __restrict__ smem,
                                         int nodeBase, int nvalid, int tid) {
    const float4* a4 = (const float4*)(aggH + (size_t)nodeBase * 64);
    for (int idx = tid; idx < nvalid * 16; idx += 256) {
        int nl = idx >> 4, c4 = (idx & 15) * 4;
        float4 a = a4[idx];
        smem[(c4 + 0) * PITCH + nl] = a.x;
        smem[(c4 + 1) * PITCH + nl] = a.y;
        smem[(c4 + 2) * PITCH + nl] = a.z;
        smem[(c4 + 3) * PITCH + nl] = a.w;
    }
    __syncthreads();
}

// ---------------------------------------------------------------------------
// kB (layers 0,1): aggH -> global_nn -> h -> next-layer u,v  (aggH aliases u)
// ---------------------------------------------------------------------------
__global__ __launch_bounds__(256) void kB(
    const float* __restrict__ aggH, const float* __restrict__ pos,
    const int* __restrict__ rowPtr,
    const float* __restrict__ lW2, const float* __restrict__ lb2,
    const float* __restrict__ gW1, const float* __restrict__ gb1,
    const float* __restrict__ gW2, const float* __restrict__ gb2,
    const float* __restrict__ W1n, const float* __restrict__ b1n,
    float* __restrict__ u, float* __restrict__ v) {
    __shared__ float smem[64 * PITCH];
    int tid = threadIdx.x;
    int lane = tid & 63;
    int wv = __builtin_amdgcn_readfirstlane(tid >> 6);
    int tb = wv * 16;
    int nodeBase = blockIdx.x * 64;
    int nvalid = min(64, N_NODES - nodeBase);
    int n = nodeBase + lane;
    bool act = lane < nvalid;

    load_agg(aggH, smem, nodeBase, nvalid, tid);
    float dg = act ? (float)(rowPtr[n + 1] - rowPtr[n]) : 0.f;

    float acc[16];
    // s1: agg = aggH@lW2 + deg*lb2
#pragma unroll
    for (int j = 0; j < 16; ++j) acc[j] = dg * lb2[tb + j];
    stage_gemv<64, 16, 64>(lW2, smem, lane, tb, acc);
    stage_store<16>(smem, lane, tb, acc, false);

    // s2: relu(@gW1 + gb1)
#pragma unroll
    for (int j = 0; j < 16; ++j) acc[j] = gb1[tb + j];
    stage_gemv<64, 16, 64>(gW1, smem, lane, tb, acc);
    stage_store<16>(smem, lane, tb, acc, true);

    // s3: h = relu(@gW2 + gb2)
#pragma unroll
    for (int j = 0; j < 16; ++j) acc[j] = gb2[tb + j];
    stage_gemv<64, 16, 64>(gW2, smem, lane, tb, acc);
    stage_store<16>(smem, lane, tb, acc, true);

    // s4: u = h@W1a(next)
#pragma unroll
    for (int j = 0; j < 16; ++j) acc[j] = 0.f;
    stage_gemv<64, 16, 64>(W1n, smem, lane, tb, acc);
    if (act) store_slice16(u, n, tb, acc);

    // s5: v = h@W1b + pos@W1c + b1(next)
#pragma unroll
    for (int j = 0; j < 16; ++j) acc[j] = b1n[tb + j];
    stage_gemv<64, 16, 64>(W1n + 64 * 64, smem, lane, tb, acc);
    float p0 = 0.f, p1 = 0.f, p2 = 0.f;
    if (act) {
        p0 = pos[(size_t)n * 3 + 0];
        p1 = pos[(size_t)n * 3 + 1];
        p2 = pos[(size_t)n * 3 + 2];
    }
    const float* __restrict__ wp = W1n + 128 * 64 + tb;
#pragma unroll
    for (int j = 0; j < 16; ++j)
        acc[j] += p0 * wp[j] + p1 * wp[64 + j] + p2 * wp[128 + j];
    if (act) store_slice16(v, n, tb, acc);
}

// ---------------------------------------------------------------------------
// kC (layer 2): aggH -> global_nn -> h -> lin1 relu lin2 -> LDS-binned readout
// ---------------------------------------------------------------------------
__global__ __launch_bounds__(256) void kC(
    const float* __restrict__ aggH, const int* __restrict__ rowPtr,
    const int* __restrict__ batch,
    const float* __restrict__ lW2, const float* __restrict__ lb2,
    const float* __restrict__ gW1, const float* __restrict__ gb1,
    const float* __restrict__ gW2, const float* __restrict__ gb2,
    const float* __restrict__ lin1W, const float* __restrict__ lin1b,
    const float* __restrict__ lin2W, const float* __restrict__ lin2b,
    float* __restrict__ out) {
    __shared__ float smem[64 * PITCH];
    __shared__ float bins[128 * 8];
    int tid = threadIdx.x;
    int lane = tid & 63;
    int wv = __builtin_amdgcn_readfirstlane(tid >> 6);
    int tb = wv * 16;
    int nodeBase = blockIdx.x * 64;
    int nvalid = min(64, N_NODES - nodeBase);
    int n = nodeBase + lane;
    bool act = lane < nvalid;

    for (int idx = tid; idx < 128 * 8; idx += 256) bins[idx] = 0.f;
    load_agg(aggH, smem, nodeBase, nvalid, tid);
    float dg = act ? (float)(rowPtr[n + 1] - rowPtr[n]) : 0.f;

    float acc[16];
#pragma unroll
    for (int j = 0; j < 16; ++j) acc[j] = dg * lb2[tb + j];
    stage_gemv<64, 16, 64>(lW2, smem, lane, tb, acc);
    stage_store<16>(smem, lane, tb, acc, false);

#pragma unroll
    for (int j = 0; j < 16; ++j) acc[j] = gb1[tb + j];
    stage_gemv<64, 16, 64>(gW1, smem, lane, tb, acc);
    stage_store<16>(smem, lane, tb, acc, true);

#pragma unroll
    for (int j = 0; j < 16; ++j) acc[j] = gb2[tb + j];
    stage_gemv<64, 16, 64>(gW2, smem, lane, tb, acc);
    stage_store<16>(smem, lane, tb, acc, true);

    // lin1: 64 -> 32, wave slice 8
    int tb8 = wv * 8;
    float acc8[8];
#pragma unroll
    for (int j = 0; j < 8; ++j) acc8[j] = lin1b[tb8 + j];
    stage_gemv<64, 8, 32>(lin1W, smem, lane, tb8, acc8);
    stage_store<8>(smem, lane, tb8, acc8, true);

    // lin2: 32 -> 8, wave slice 2
    int tb2 = wv * 2;
    float acc2[2];
#pragma unroll
    for (int j = 0; j < 2; ++j) acc2[j] = lin2b[tb2 + j];
    stage_gemv<32, 2, 8>(lin2W, smem, lane, tb2, acc2);

    // readout: bin per (graph - gmin, ch) in LDS, then few global atomics
    int gmin = batch[nodeBase];
    if (act) {
        int g = batch[n] - gmin;
        atomicAdd(&bins[g * 8 + tb2 + 0], acc2[0]);
        atomicAdd(&bins[g * 8 + tb2 + 1], acc2[1]);
    }
    __syncthreads();
    int gmax = batch[nodeBase + nvalid - 1];
    int nb8 = (gmax - gmin + 1) * 8;
    for (int idx = tid; idx < nb8; idx += 256)
        atomAddF(&out[gmin * 8 + idx], bins[idx]);
}

// ---------------------------------------------------------------------------
// launch
// ---------------------------------------------------------------------------
extern "C" void kernel_launch(void* const* d_in, const int* in_sizes, int n_in,
                              void* d_out, int out_size, void* d_ws, size_t ws_size,
                              hipStream_t stream) {
    const float* x     = (const float*)d_in[0];
    const float* pos   = (const float*)d_in[1];
    const int*   ei    = (const int*)d_in[2];
    const int*   batch = (const int*)d_in[3];
    const float* nW1   = (const float*)d_in[4];
    const float* nb1   = (const float*)d_in[5];
    const float* nW2   = (const float*)d_in[6];
    const float* nb2   = (const float*)d_in[7];
    const float* lW1   = (const float*)d_in[8];
    const float* lb1   = (const float*)d_in[9];
    const float* lW2   = (const float*)d_in[10];
    const float* lb2   = (const float*)d_in[11];
    const float* gW1   = (const float*)d_in[12];
    const float* gb1   = (const float*)d_in[13];
    const float* gW2   = (const float*)d_in[14];
    const float* gb2   = (const float*)d_in[15];
    const float* lin1W = (const float*)d_in[16];
    const float* lin1b = (const float*)d_in[17];
    const float* lin2W = (const float*)d_in[18];
    const float* lin2b = (const float*)d_in[19];
    float* out = (float*)d_out;

    float* u       = (float*)d_ws;                        // N*64 (also aggH)
    float* v       = u + (size_t)N_NODES * 64;            // N*64
    int*   cursor  = (int*)(v + (size_t)N_NODES * 64);    // N (also histogram)
    int*   rowPtr  = cursor + N_NODES;                    // N+1
    int*   srcList = rowPtr + N_NODES + 1;                // E
    int*   blockSums = srcList + N_EDGES;                 // 256
    int*   chunkOff  = blockSums + 256;                   // 256
    float* aggH = u;

    const int nodeBlocks = (N_NODES + 63) / 64;
    const int edgeBlocks = (N_EDGES + 255) / 256;
    const int aggBlocks  = (N_NODES * 64 + 255) / 256;

    hipMemsetAsync(cursor, 0, N_NODES * sizeof(int), stream);
    hipMemsetAsync(out, 0, (size_t)out_size * sizeof(float), stream);

    kDeg<<<edgeBlocks, 256, 0, stream>>>(ei, cursor);
    kBlockSum<<<NCHUNK, 256, 0, stream>>>(cursor, blockSums);
    kScanSmall<<<1, 256, 0, stream>>>(blockSums, chunkOff);
    kRowPtr<<<NCHUNK, 256, 0, stream>>>(cursor, chunkOff, rowPtr, cursor);
    kScatter<<<edgeBlocks, 256, 0, stream>>>(ei, cursor, srcList);

    kA<<<nodeBlocks, 256, 0, stream>>>(x, pos, nW1, nb1, nW2, nb2,
                                       lW1, lb1, u, v);

    for (int l = 0; l < 3; ++l) {
        kAgg<<<aggBlocks, 256, 0, stream>>>(rowPtr, srcList, u, v, aggH);
        if (l < 2) {
            kB<<<nodeBlocks, 256, 0, stream>>>(
                aggH, pos, rowPtr,
                lW2 + l * 64 * 64, lb2 + l * 64,
                gW1 + l * 64 * 64, gb1 + l * 64,
                gW2 + l * 64 * 64, gb2 + l * 64,
                lW1 + (l + 1) * 131 * 64, lb1 + (l + 1) * 64,
                u, v);
        } else {
            kC<<<nodeBlocks, 256, 0, stream>>>(
                aggH, rowPtr, batch,
                lW2 + l * 64 * 64, lb2 + l * 64,
                gW1 + l * 64 * 64, gb1 + l * 64,
                gW2 + l * 64 * 64, gb2 + l * 64,
                lin1W, lin1b, lin2W, lin2b, out);
        }
    }
}

// Round 4
// 434.966 us; speedup vs baseline: 6.3533x; 1.4790x over previous
//
#include <hip/hip_runtime.h>

#define N_NODES 50000
#define N_EDGES 800000
#define NGRAPH  128
#define NCHUNK  ((N_NODES + 255) / 256)
#define XPITCH  72   // ushort pitch for 64-wide LDS activation rows (16B-aligned, 2-way banks)

typedef short bf16x8 __attribute__((ext_vector_type(8)));
typedef float f32x4  __attribute__((ext_vector_type(4)));

// ---------------------------------------------------------------------------
// helpers
// ---------------------------------------------------------------------------

__device__ __forceinline__ float atomAddF(float* p, float v) {
#if defined(__gfx950__) || defined(__AMDGCN__)
    return unsafeAtomicAdd(p, v);
#else
    return atomicAdd(p, v);
#endif
}

__device__ __forceinline__ unsigned short f2bf(float x) {  // RNE f32 -> bf16
    unsigned u = __builtin_bit_cast(unsigned, x);
    u += 0x7fffu + ((u >> 16) & 1u);
    return (unsigned short)(u >> 16);
}
__device__ __forceinline__ float bf2f(unsigned short h) {
    return __builtin_bit_cast(float, (unsigned)h << 16);
}

// One 16x16 C-tile: acc += X[16mt..+16][K] @ WT^T[16nt..+16] over NKC k-chunks.
// A-frag: lane holds A[m=16mt+(lane&15)][k=quad*8+j]  (ds_read_b128)
// B-frag: lane holds B[k=quad*8+j][n=16nt+(lane&15)] from WT[n][k] rows (global 16B)
template<int NKC, int KROW>
__device__ __forceinline__ f32x4 tile_mm(const unsigned short* __restrict__ Xlds,
                                         const unsigned short* __restrict__ WT,
                                         int mt, int nt, int lane, f32x4 acc) {
    int col  = lane & 15;
    int quad = lane >> 4;
    const unsigned short* xp = Xlds + (mt * 16 + col) * XPITCH + quad * 8;
    const unsigned short* wp = WT + (nt * 16 + col) * KROW + quad * 8;
#pragma unroll
    for (int c = 0; c < NKC; ++c) {
        bf16x8 a = *(const bf16x8*)(xp + c * 32);
        bf16x8 b = *(const bf16x8*)(wp + c * 32);
        acc = __builtin_amdgcn_mfma_f32_16x16x32_bf16(a, b, acc, 0, 0, 0);
    }
    return acc;
}

__device__ __forceinline__ f32x4 mk4(float b) { f32x4 a = {b, b, b, b}; return a; }

// C/D layout: col=lane&15 (=n offset), row=quad*4+reg (=m offset)
__device__ __forceinline__ void ep_lds(unsigned short* __restrict__ Xo, int wv, int nt,
                                       int lane, f32x4 acc, bool relu) {
    int col = lane & 15, quad = lane >> 4;
#pragma unroll
    for (int r = 0; r < 4; ++r) {
        float xv = acc[r];
        if (relu) xv = fmaxf(xv, 0.f);
        Xo[(wv * 16 + quad * 4 + r) * XPITCH + nt * 16 + col] = f2bf(xv);
    }
}

__device__ __forceinline__ void ep_glob(unsigned short* __restrict__ g, int nodeBase,
                                        int nvalid, int wv, int nt, int lane, f32x4 acc) {
    int col = lane & 15, quad = lane >> 4;
#pragma unroll
    for (int r = 0; r < 4; ++r) {
        int nl = wv * 16 + quad * 4 + r;
        if (nl < nvalid)
            g[(size_t)(nodeBase + nl) * 64 + nt * 16 + col] = f2bf(acc[r]);
    }
}

// ---------------------------------------------------------------------------
// weight prep: transpose + bf16-convert all matrices into WT (B-operand layout)
// layout (ushort offsets):
//   nW1T   @ 0      : 64 x 32  (k>=16 zero)
//   nW2T   @ 2048   : 64 x 64
//   layer l blocks @ 6144 + l*20480, each: aT, bT, lW2T, gW1T, gW2T (64x64 each)
//   lin1T  @ 67584  : 32 x 64
//   lin2T  @ 69632  : 16 x 32  (n>=8 zero)
// ---------------------------------------------------------------------------
#define OFF_NW1T  0
#define OFF_NW2T  2048
#define OFF_LYR   6144
#define LYR_SZ    20480
#define OFF_LIN1T 67584
#define OFF_LIN2T 69632
#define WT_TOTAL  70144

__global__ __launch_bounds__(256) void kPrep(
    const float* __restrict__ nW1, const float* __restrict__ nW2,
    const float* __restrict__ lW1, const float* __restrict__ lW2,
    const float* __restrict__ gW1, const float* __restrict__ gW2,
    const float* __restrict__ lin1W, const float* __restrict__ lin2W,
    unsigned short* __restrict__ WT) {
    int i = blockIdx.x * 256 + threadIdx.x;
    if (i >= WT_TOTAL) return;
    int j = i;
    if (j < 2048) {                                  // nW1T
        int n = j >> 5, k = j & 31;
        WT[i] = (k < 16) ? f2bf(nW1[k * 64 + n]) : 0;
        return;
    }
    j -= 2048;
    if (j < 4096) {                                  // nW2T
        int n = j >> 6, k = j & 63;
        WT[i] = f2bf(nW2[k * 64 + n]);
        return;
    }
    j -= 4096;
    if (j < 3 * LYR_SZ) {                            // per-layer
        int l = j / LYR_SZ;  j -= l * LYR_SZ;
        int m = j >> 12;     j &= 4095;              // which of 5 mats
        int n = j >> 6, k = j & 63;
        const float* src;
        if (m == 0)      src = lW1 + (size_t)l * 131 * 64;            // aT
        else if (m == 1) src = lW1 + (size_t)l * 131 * 64 + 64 * 64;  // bT
        else if (m == 2) src = lW2 + (size_t)l * 4096;
        else if (m == 3) src = gW1 + (size_t)l * 4096;
        else             src = gW2 + (size_t)l * 4096;
        WT[i] = f2bf(src[k * 64 + n]);
        return;
    }
    j -= 3 * LYR_SZ;
    if (j < 2048) {                                  // lin1T
        int n = j >> 6, k = j & 63;
        WT[i] = f2bf(lin1W[k * 32 + n]);
        return;
    }
    j -= 2048;
    {                                                // lin2T
        int n = j >> 5, k = j & 31;
        WT[i] = (n < 8) ? f2bf(lin2W[k * 8 + n]) : 0;
    }
}

// ---------------------------------------------------------------------------
// CSR build: histogram -> 2-level exclusive scan -> scatter
// ---------------------------------------------------------------------------
__global__ void kDeg(const int* __restrict__ ei, int* __restrict__ cnt) {
    int e = blockIdx.x * blockDim.x + threadIdx.x;
    if (e < N_EDGES) atomicAdd(&cnt[ei[N_EDGES + e]], 1);
}

__global__ __launch_bounds__(256) void kBlockSum(const int* __restrict__ cnt,
                                                 int* __restrict__ blockSums) {
    __shared__ int s[256];
    int i = threadIdx.x;
    int n = blockIdx.x * 256 + i;
    s[i] = (n < N_NODES) ? cnt[n] : 0;
    __syncthreads();
#pragma unroll
    for (int off = 128; off > 0; off >>= 1) {
        if (i < off) s[i] += s[i + off];
        __syncthreads();
    }
    if (i == 0) blockSums[blockIdx.x] = s[0];
}

__global__ __launch_bounds__(256) void kScanSmall(const int* __restrict__ blockSums,
                                                  int* __restrict__ chunkOff) {
    __shared__ int s[256];
    int i = threadIdx.x;
    int val = (i < NCHUNK) ? blockSums[i] : 0;
    s[i] = val;
    __syncthreads();
#pragma unroll
    for (int off = 1; off < 256; off <<= 1) {
        int t = (i >= off) ? s[i - off] : 0;
        __syncthreads();
        s[i] += t;
        __syncthreads();
    }
    chunkOff[i] = s[i] - val;
}

__global__ __launch_bounds__(256) void kRowPtr(const int* __restrict__ cnt,
                                               const int* __restrict__ chunkOff,
                                               int* __restrict__ rowPtr,
                                               int* __restrict__ cursor) {
    __shared__ int s[256];
    int i = threadIdx.x;
    int n = blockIdx.x * 256 + i;
    int val = (n < N_NODES) ? cnt[n] : 0;
    s[i] = val;
    __syncthreads();
#pragma unroll
    for (int off = 1; off < 256; off <<= 1) {
        int t = (i >= off) ? s[i - off] : 0;
        __syncthreads();
        s[i] += t;
        __syncthreads();
    }
    if (n < N_NODES) {
        int ex = chunkOff[blockIdx.x] + s[i] - val;
        rowPtr[n] = ex;
        cursor[n] = ex;
        if (n == N_NODES - 1) rowPtr[N_NODES] = ex + val;
    }
}

__global__ void kScatter(const int* __restrict__ ei, int* __restrict__ cursor,
                         int* __restrict__ srcList) {
    int e = blockIdx.x * blockDim.x + threadIdx.x;
    if (e >= N_EDGES) return;
    int s = ei[e];
    int d = ei[N_EDGES + e];
    int idx = atomicAdd(&cursor[d], 1);
    srcList[idx] = s;
}

// ---------------------------------------------------------------------------
// aggregation (bf16 u,v,aggH): one wave per node, lane = channel; zero atomics
// aggH aliases u (row read before written, one wave owns row n exclusively)
// ---------------------------------------------------------------------------
__global__ __launch_bounds__(256) void kAgg(const int* __restrict__ rowPtr,
                                            const int* __restrict__ srcList,
                                            const unsigned short* __restrict__ u,
                                            const unsigned short* __restrict__ v,
                                            unsigned short* __restrict__ aggH) {
    int gt = blockIdx.x * 256 + threadIdx.x;
    int n = gt >> 6;
    int lane = gt & 63;
    if (n >= N_NODES) return;
    float ut = bf2f(u[(size_t)n * 64 + lane]);
    int b = rowPtr[n], e = rowPtr[n + 1];
    float acc = 0.f;
    int i = b;
    for (; i + 1 < e; i += 2) {
        int s0 = srcList[i];
        int s1 = srcList[i + 1];
        float v0 = bf2f(v[(size_t)s0 * 64 + lane]);
        float v1 = bf2f(v[(size_t)s1 * 64 + lane]);
        acc += fmaxf(ut + v0, 0.f) + fmaxf(ut + v1, 0.f);
    }
    if (i < e)
        acc += fmaxf(ut + bf2f(v[(size_t)srcList[i] * 64 + lane]), 0.f);
    aggH[(size_t)n * 64 + lane] = f2bf(acc);
}

// ---------------------------------------------------------------------------
// kA: node_lin (16->64 relu ->64) then u = h@W1a, v = h@W1b + pos@W1c + b1
// 64 nodes/block, 4 waves (MFMA): wave = m-tile, nt loop over 4 n-tiles
// ---------------------------------------------------------------------------
__global__ __launch_bounds__(256) void kA(
    const float* __restrict__ x, const float* __restrict__ pos,
    const unsigned short* __restrict__ WT,
    const float* __restrict__ nb1, const float* __restrict__ nb2,
    const float* __restrict__ lW1f, const float* __restrict__ lb1,
    unsigned short* __restrict__ u, unsigned short* __restrict__ v) {
    __shared__ unsigned short Xa[64 * XPITCH];
    __shared__ unsigned short Xb[64 * XPITCH];
    __shared__ float posS[192];
    int tid = threadIdx.x;
    int lane = tid & 63;
    int wv = __builtin_amdgcn_readfirstlane(tid >> 6);
    int nodeBase = blockIdx.x * 64;
    int nvalid = min(64, N_NODES - nodeBase);
    int col = lane & 15;

    // stage x -> Xa (bf16, k 16..31 zero), pos -> posS
    for (int idx = tid; idx < 64 * 32; idx += 256) {
        int rowi = idx >> 5, k = idx & 31;
        float val = (k < 16 && rowi < nvalid) ? x[(size_t)(nodeBase + rowi) * 16 + k] : 0.f;
        Xa[rowi * XPITCH + k] = f2bf(val);
    }
    for (int idx = tid; idx < 192; idx += 256)
        posS[idx] = (idx < nvalid * 3) ? pos[(size_t)nodeBase * 3 + idx] : 0.f;
    __syncthreads();

    // s1: relu(x @ nW1 + nb1) -> Xb
#pragma unroll
    for (int nt = 0; nt < 4; ++nt) {
        f32x4 acc = tile_mm<1, 32>(Xa, WT + OFF_NW1T, wv, nt, lane, mk4(nb1[nt * 16 + col]));
        ep_lds(Xb, wv, nt, lane, acc, true);
    }
    __syncthreads();

    // s2: h = Xb @ nW2 + nb2 -> Xa
#pragma unroll
    for (int nt = 0; nt < 4; ++nt) {
        f32x4 acc = tile_mm<2, 64>(Xb, WT + OFF_NW2T, wv, nt, lane, mk4(nb2[nt * 16 + col]));
        ep_lds(Xa, wv, nt, lane, acc, false);
    }
    __syncthreads();

    const unsigned short* aT = WT + OFF_LYR;            // layer 0 aT
    const unsigned short* bT = aT + 4096;               // layer 0 bT
    const float* W1c = lW1f + 128 * 64;                 // layer 0 pos rows (f32)

    // s3: u = h @ W1a
#pragma unroll
    for (int nt = 0; nt < 4; ++nt) {
        f32x4 acc = tile_mm<2, 64>(Xa, aT, wv, nt, lane, mk4(0.f));
        ep_glob(u, nodeBase, nvalid, wv, nt, lane, acc);
    }
    // s4: v = h @ W1b + pos @ W1c + b1
#pragma unroll
    for (int nt = 0; nt < 4; ++nt) {
        int ch = nt * 16 + col;
        f32x4 acc = tile_mm<2, 64>(Xa, bT, wv, nt, lane, mk4(lb1[ch]));
        float w0 = W1c[ch], w1 = W1c[64 + ch], w2 = W1c[128 + ch];
        int quad = lane >> 4;
#pragma unroll
        for (int r = 0; r < 4; ++r) {
            int nl = wv * 16 + quad * 4 + r;
            acc[r] += posS[nl * 3] * w0 + posS[nl * 3 + 1] * w1 + posS[nl * 3 + 2] * w2;
        }
        ep_glob(v, nodeBase, nvalid, wv, nt, lane, acc);
    }
}

// ---------------------------------------------------------------------------
// kB (layers 0,1): aggH -> local_W2/global_nn -> h -> next-layer u,v
// ---------------------------------------------------------------------------
__global__ __launch_bounds__(256) void kB(
    const unsigned short* __restrict__ aggH, const float* __restrict__ pos,
    const int* __restrict__ rowPtr, const unsigned short* __restrict__ WT,
    int l,
    const float* __restrict__ lb2, const float* __restrict__ gb1,
    const float* __restrict__ gb2,
    const float* __restrict__ lW1f_next, const float* __restrict__ b1n,
    unsigned short* __restrict__ u, unsigned short* __restrict__ v) {
    __shared__ unsigned short Xa[64 * XPITCH];
    __shared__ unsigned short Xb[64 * XPITCH];
    __shared__ float posS[192];
    __shared__ float degS[64];
    int tid = threadIdx.x;
    int lane = tid & 63;
    int wv = __builtin_amdgcn_readfirstlane(tid >> 6);
    int nodeBase = blockIdx.x * 64;
    int nvalid = min(64, N_NODES - nodeBase);
    int col = lane & 15;
    int quad = lane >> 4;

    const unsigned short* LYR = WT + OFF_LYR + (size_t)l * LYR_SZ;
    const unsigned short* lW2T = LYR + 2 * 4096;
    const unsigned short* gW1T = LYR + 3 * 4096;
    const unsigned short* gW2T = LYR + 4 * 4096;
    const unsigned short* aTn = WT + OFF_LYR + (size_t)(l + 1) * LYR_SZ;
    const unsigned short* bTn = aTn + 4096;

    // stage aggH -> Xa (16B chunks), pos, deg
    const uint4* ag = (const uint4*)(aggH + (size_t)nodeBase * 64);
    for (int idx = tid; idx < 512; idx += 256) {
        int rowi = idx >> 3, seg = idx & 7;
        uint4 d = (rowi < nvalid) ? ag[idx] : make_uint4(0u, 0u, 0u, 0u);
        *(uint4*)&Xa[rowi * XPITCH + seg * 8] = d;
    }
    for (int idx = tid; idx < 192; idx += 256)
        posS[idx] = (idx < nvalid * 3) ? pos[(size_t)nodeBase * 3 + idx] : 0.f;
    if (tid < 64)
        degS[tid] = (tid < nvalid)
            ? (float)(rowPtr[nodeBase + tid + 1] - rowPtr[nodeBase + tid]) : 0.f;
    __syncthreads();

    // s1: agg = aggH @ lW2 + deg*lb2 -> Xb
#pragma unroll
    for (int nt = 0; nt < 4; ++nt) {
        float b = lb2[nt * 16 + col];
        f32x4 init;
        float4 dg = *(float4*)&degS[wv * 16 + quad * 4];
        init[0] = dg.x * b; init[1] = dg.y * b; init[2] = dg.z * b; init[3] = dg.w * b;
        f32x4 acc = tile_mm<2, 64>(Xa, lW2T, wv, nt, lane, init);
        ep_lds(Xb, wv, nt, lane, acc, false);
    }
    __syncthreads();

    // s2: relu(@gW1 + gb1) -> Xa
#pragma unroll
    for (int nt = 0; nt < 4; ++nt) {
        f32x4 acc = tile_mm<2, 64>(Xb, gW1T, wv, nt, lane, mk4(gb1[nt * 16 + col]));
        ep_lds(Xa, wv, nt, lane, acc, true);
    }
    __syncthreads();

    // s3: h = relu(@gW2 + gb2) -> Xb
#pragma unroll
    for (int nt = 0; nt < 4; ++nt) {
        f32x4 acc = tile_mm<2, 64>(Xa, gW2T, wv, nt, lane, mk4(gb2[nt * 16 + col]));
        ep_lds(Xb, wv, nt, lane, acc, true);
    }
    __syncthreads();

    // s4: u = h @ aT(next)
#pragma unroll
    for (int nt = 0; nt < 4; ++nt) {
        f32x4 acc = tile_mm<2, 64>(Xb, aTn, wv, nt, lane, mk4(0.f));
        ep_glob(u, nodeBase, nvalid, wv, nt, lane, acc);
    }
    // s5: v = h @ bT(next) + pos @ W1c(next) + b1(next)
    const float* W1c = lW1f_next + 128 * 64;
#pragma unroll
    for (int nt = 0; nt < 4; ++nt) {
        int ch = nt * 16 + col;
        f32x4 acc = tile_mm<2, 64>(Xb, bTn, wv, nt, lane, mk4(b1n[ch]));
        float w0 = W1c[ch], w1 = W1c[64 + ch], w2 = W1c[128 + ch];
#pragma unroll
        for (int r = 0; r < 4; ++r) {
            int nl = wv * 16 + quad * 4 + r;
            acc[r] += posS[nl * 3] * w0 + posS[nl * 3 + 1] * w1 + posS[nl * 3 + 2] * w2;
        }
        ep_glob(v, nodeBase, nvalid, wv, nt, lane, acc);
    }
}

// ---------------------------------------------------------------------------
// kC (layer 2): aggH -> global_nn -> h -> lin1 relu lin2 -> LDS-binned readout
// ---------------------------------------------------------------------------
__global__ __launch_bounds__(256) void kC(
    const unsigned short* __restrict__ aggH, const int* __restrict__ rowPtr,
    const int* __restrict__ batch, const unsigned short* __restrict__ WT,
    const float* __restrict__ lb2, const float* __restrict__ gb1,
    const float* __restrict__ gb2,
    const float* __restrict__ lin1b, const float* __restrict__ lin2b,
    float* __restrict__ out) {
    __shared__ unsigned short Xa[64 * XPITCH];
    __shared__ unsigned short Xb[64 * XPITCH];
    __shared__ float degS[64];
    __shared__ int batchS[64];
    __shared__ float bins[128 * 8];
    int tid = threadIdx.x;
    int lane = tid & 63;
    int wv = __builtin_amdgcn_readfirstlane(tid >> 6);
    int nodeBase = blockIdx.x * 64;
    int nvalid = min(64, N_NODES - nodeBase);
    int col = lane & 15;
    int quad = lane >> 4;

    const unsigned short* LYR = WT + OFF_LYR + 2 * LYR_SZ;
    const unsigned short* lW2T = LYR + 2 * 4096;
    const unsigned short* gW1T = LYR + 3 * 4096;
    const unsigned short* gW2T = LYR + 4 * 4096;
    const unsigned short* lin1T = WT + OFF_LIN1T;
    const unsigned short* lin2T = WT + OFF_LIN2T;

    const uint4* ag = (const uint4*)(aggH + (size_t)nodeBase * 64);
    for (int idx = tid; idx < 512; idx += 256) {
        int rowi = idx >> 3, seg = idx & 7;
        uint4 d = (rowi < nvalid) ? ag[idx] : make_uint4(0u, 0u, 0u, 0u);
        *(uint4*)&Xa[rowi * XPITCH + seg * 8] = d;
    }
    if (tid < 64) {
        degS[tid] = (tid < nvalid)
            ? (float)(rowPtr[nodeBase + tid + 1] - rowPtr[nodeBase + tid]) : 0.f;
        batchS[tid] = (tid < nvalid) ? batch[nodeBase + tid] : batch[N_NODES - 1];
    }
    for (int idx = tid; idx < 128 * 8; idx += 256) bins[idx] = 0.f;
    __syncthreads();

#pragma unroll
    for (int nt = 0; nt < 4; ++nt) {
        float b = lb2[nt * 16 + col];
        f32x4 init;
        float4 dg = *(float4*)&degS[wv * 16 + quad * 4];
        init[0] = dg.x * b; init[1] = dg.y * b; init[2] = dg.z * b; init[3] = dg.w * b;
        f32x4 acc = tile_mm<2, 64>(Xa, lW2T, wv, nt, lane, init);
        ep_lds(Xb, wv, nt, lane, acc, false);
    }
    __syncthreads();
#pragma unroll
    for (int nt = 0; nt < 4; ++nt) {
        f32x4 acc = tile_mm<2, 64>(Xb, gW1T, wv, nt, lane, mk4(gb1[nt * 16 + col]));
        ep_lds(Xa, wv, nt, lane, acc, true);
    }
    __syncthreads();
#pragma unroll
    for (int nt = 0; nt < 4; ++nt) {
        f32x4 acc = tile_mm<2, 64>(Xa, gW2T, wv, nt, lane, mk4(gb2[nt * 16 + col]));
        ep_lds(Xb, wv, nt, lane, acc, true);
    }
    __syncthreads();

    // lin1: 64 -> 32 (2 n-tiles) -> Xa
#pragma unroll
    for (int nt = 0; nt < 2; ++nt) {
        f32x4 acc = tile_mm<2, 64>(Xb, lin1T, wv, nt, lane, mk4(lin1b[nt * 16 + col]));
        ep_lds(Xa, wv, nt, lane, acc, true);
    }
    __syncthreads();

    // lin2: 32 -> 8 (1 n-tile, cols 8..15 are zero rows of lin2T)
    {
        f32x4 acc = tile_mm<1, 32>(Xa, lin2T, wv, 0, lane,
                                   mk4(col < 8 ? lin2b[col] : 0.f));
        int gmin = batch[nodeBase];
        if (col < 8) {
#pragma unroll
            for (int r = 0; r < 4; ++r) {
                int nl = wv * 16 + quad * 4 + r;
                if (nl < nvalid)
                    atomicAdd(&bins[(batchS[nl] - gmin) * 8 + col], acc[r]);
            }
        }
        __syncthreads();
        int nb8 = (batchS[nvalid - 1] - gmin + 1) * 8;
        for (int idx = tid; idx < nb8; idx += 256)
            atomAddF(&out[gmin * 8 + idx], bins[idx]);
    }
}

// ---------------------------------------------------------------------------
// launch
// ---------------------------------------------------------------------------
extern "C" void kernel_launch(void* const* d_in, const int* in_sizes, int n_in,
                              void* d_out, int out_size, void* d_ws, size_t ws_size,
                              hipStream_t stream) {
    const float* x     = (const float*)d_in[0];
    const float* pos   = (const float*)d_in[1];
    const int*   ei    = (const int*)d_in[2];
    const int*   batch = (const int*)d_in[3];
    const float* nW1   = (const float*)d_in[4];
    const float* nb1   = (const float*)d_in[5];
    const float* nW2   = (const float*)d_in[6];
    const float* nb2   = (const float*)d_in[7];
    const float* lW1   = (const float*)d_in[8];
    const float* lb1   = (const float*)d_in[9];
    const float* lW2   = (const float*)d_in[10];
    const float* lb2   = (const float*)d_in[11];
    const float* gW1   = (const float*)d_in[12];
    const float* gb1   = (const float*)d_in[13];
    const float* gW2   = (const float*)d_in[14];
    const float* gb2   = (const float*)d_in[15];
    const float* lin1W = (const float*)d_in[16];
    const float* lin1b = (const float*)d_in[17];
    const float* lin2W = (const float*)d_in[18];
    const float* lin2b = (const float*)d_in[19];
    float* out = (float*)d_out;

    // workspace (u doubles as aggH)
    unsigned short* u  = (unsigned short*)d_ws;          // N*64 bf16
    unsigned short* v  = u + (size_t)N_NODES * 64;       // N*64 bf16
    unsigned short* WT = v + (size_t)N_NODES * 64;       // WT_TOTAL bf16
    int* cursor  = (int*)(WT + WT_TOTAL);                // N (histogram/cursor)
    int* rowPtr  = cursor + N_NODES;                     // N+1
    int* srcList = rowPtr + N_NODES + 1;                 // E
    int* blockSums = srcList + N_EDGES;                  // 256
    int* chunkOff  = blockSums + 256;                    // 256
    unsigned short* aggH = u;

    const int nodeBlocks = (N_NODES + 63) / 64;
    const int edgeBlocks = (N_EDGES + 255) / 256;
    const int aggBlocks  = (N_NODES * 64 + 255) / 256;

    hipMemsetAsync(cursor, 0, N_NODES * sizeof(int), stream);
    hipMemsetAsync(out, 0, (size_t)out_size * sizeof(float), stream);

    kPrep<<<(WT_TOTAL + 255) / 256, 256, 0, stream>>>(nW1, nW2, lW1, lW2, gW1, gW2,
                                                      lin1W, lin2W, WT);
    kDeg<<<edgeBlocks, 256, 0, stream>>>(ei, cursor);
    kBlockSum<<<NCHUNK, 256, 0, stream>>>(cursor, blockSums);
    kScanSmall<<<1, 256, 0, stream>>>(blockSums, chunkOff);
    kRowPtr<<<NCHUNK, 256, 0, stream>>>(cursor, chunkOff, rowPtr, cursor);
    kScatter<<<edgeBlocks, 256, 0, stream>>>(ei, cursor, srcList);

    kA<<<nodeBlocks, 256, 0, stream>>>(x, pos, WT, nb1, nb2, lW1, lb1, u, v);

    for (int l = 0; l < 3; ++l) {
        kAgg<<<aggBlocks, 256, 0, stream>>>(rowPtr, srcList, u, v, aggH);
        if (l < 2) {
            kB<<<nodeBlocks, 256, 0, stream>>>(
                aggH, pos, rowPtr, WT, l,
                lb2 + l * 64, gb1 + l * 64, gb2 + l * 64,
                lW1 + (size_t)(l + 1) * 131 * 64, lb1 + (l + 1) * 64,
                u, v);
        } else {
            kC<<<nodeBlocks, 256, 0, stream>>>(
                aggH, rowPtr, batch, WT,
                lb2 + l * 64, gb1 + l * 64, gb2 + l * 64,
                lin1b, lin2b, out);
        }
    }
}